// Round 5
// baseline (8775.495 us; speedup 1.0000x reference)
//
#include <hip/hip_runtime.h>
#include <math.h>

// Per-sample fully-fused iterated CNN. Persistent blocks, 256 threads, atomic
// work-stealing. 4 blocks/CU at FULL fp32: rounds 3/4 proved any mantissa
// compression (fp16 overflows; bf16 0.4% rounding) is chaotically amplified
// by the ~10x/iter state growth -> 11x over threshold. LDS diet instead:
//  - rp32 removed: conv1 reads rp40 (-1 pads) with exact algebraic pad
//    correction folded into acc init (true = computed + sum_oob(w)).
//  - h1p pad rows removed (8x28x31): conv2 skips rr outside [2,29] (taps 0).
//  - w1/b1/b2 read from global (L1-resident broadcast, like w2 already).
// Struct = 40720 B -> 40960 rounded (512B granularity) = exactly 160KB/4.
// VGPR pinned <=128 via amdgpu_waves_per_eu(4) (16 waves/CU needs <=128).
#define RP40S 44   // (-1)-padded 40x44 state (16B-aligned rows)
#define H1W   31   // h1 col stride: 2 left pads + 28 + 1 right pad (zeros);
                   // 31 = -1 mod 32 -> conv2's 15 (pyg,pxg) read bases worst
                   // 2-way bank-aliased (free on CDNA4)

struct SharedBufs {
    float rp40[40*RP40S];   //  7040 B  (state, -1 pads, persists)
    float h1p[8*28*H1W];    // 27776 B  (conv1 activations, fp32, zero col-pads)
    float pbuf[1296];       //  5184 B  (pooled feats; reused as new-r tmp[784])
    float wker[169];        //   676 B
    float num_s[10];        //    40 B
    int   next;             //     4 B  (work-stealing broadcast slot)
};                          // 40720 B

template<int OUT>
__device__ __forceinline__ void fc_tanh(const float* __restrict__ Wg,
                                        const float* __restrict__ bg,
                                        const float* __restrict__ p,
                                        float* __restrict__ dst, int tid)
{
    if (tid < OUT) {
        float a[8];
        #pragma unroll
        for (int u = 0; u < 8; ++u) a[u] = 0.f;
        #pragma unroll 2
        for (int i0 = 0; i0 < 1296; i0 += 8) {
            #pragma unroll
            for (int u = 0; u < 8; ++u)
                a[u] = fmaf(p[i0+u], Wg[(i0+u)*OUT + tid], a[u]);
        }
        float s = ((a[0]+a[1])+(a[2]+a[3])) + ((a[4]+a[5])+(a[6]+a[7])) + bg[tid];
        dst[tid] = tanhf(s);
    }
}

__device__ __forceinline__ void trunk_pass(SharedBufs& sb, int tid,
                                           const float* __restrict__ w1g,
                                           const float* __restrict__ b1g,
                                           const float* __restrict__ w2g,
                                           const float* __restrict__ b2g)
{
    // ---- conv1 5x5 pad2 + relu -> h1p. thread = (y, c): c=tid&7 so a y-group
    // of 8 lanes broadcasts the same rp40 row (row spacing 44 = 12 mod 32:
    // the 8 distinct y-rows per wave hit 8 distinct banks).
    // Reads the -1-padded rp40 (pad depth <=2 used); exact correction:
    // true = computed + sum_oob(w). sum_oob(y,x) = S_all - RectSum(y,x) where
    // RectSum = sum over in-bounds taps; decomposed via row-restricted column
    // sums csR[kx] (rows kyLo..kyHi) -> corr = corrI + edge col terms.
    if (tid < 224) {
        const int c = tid & 7;
        const int y = tid >> 3;
        float wreg[25];
        #pragma unroll
        for (int t = 0; t < 25; ++t) wreg[t] = w1g[c*25 + t];
        float csR[5];
        float S_all = 0.f, SR = 0.f;
        #pragma unroll
        for (int kx = 0; kx < 5; ++kx) {
            float a = wreg[kx] + wreg[5+kx] + wreg[10+kx] + wreg[15+kx] + wreg[20+kx];
            float ex = 0.f;
            if (y == 0)       ex = wreg[kx] + wreg[5+kx];   // rows ky=0,1 oob
            else if (y == 1)  ex = wreg[kx];                // row ky=0 oob
            if (y == 26)      ex += wreg[20+kx];            // row ky=4 oob
            else if (y == 27) ex += wreg[15+kx] + wreg[20+kx];
            csR[kx] = a - ex;
            S_all += a; SR += csR[kx];
        }
        const float corrI = S_all - SR;       // rows-oob, all kx (0 for inner y)
        const float bias  = b1g[c];
        float acc[28];
        #pragma unroll
        for (int x = 0; x < 28; ++x) acc[x] = bias + corrI;
        acc[0]  += csR[0] + csR[1];           // cols kx=0,1 oob at x=0
        acc[1]  += csR[0];
        acc[26] += csR[4];
        acc[27] += csR[3] + csR[4];
        #pragma unroll
        for (int ky = 0; ky < 5; ++ky) {
            // rp40 rows y+4..y+8, cols 4..35 (state cols -2..29), 16B-aligned
            const float4* rr = (const float4*)&sb.rp40[(y+4+ky)*RP40S + 4];
            float rv[32];
            #pragma unroll
            for (int q = 0; q < 8; ++q) {
                float4 t = rr[q];
                rv[q*4+0]=t.x; rv[q*4+1]=t.y; rv[q*4+2]=t.z; rv[q*4+3]=t.w;
            }
            #pragma unroll
            for (int kx = 0; kx < 5; ++kx) {
                const float w = wreg[ky*5+kx];
                #pragma unroll
                for (int x = 0; x < 28; ++x) acc[x] = fmaf(w, rv[x+kx], acc[x]);
            }
        }
        float* hp = &sb.h1p[(c*28 + y)*H1W + 2];
        #pragma unroll
        for (int x = 0; x < 28; ++x) hp[x] = fmaxf(acc[x], 0.f);
    }
    __syncthreads();

    // ---- conv2 5x5 pad2 + relu + maxpool3 -> pbuf[1296].
    // thread computes a 2(py) x 3(px) group of pooled outputs: 54 conv accs.
    // 240 threads cover 16c x 5pyg x 3pxg. w2/b2 from global (L1-resident).
    // h1p has NO row pads: rr outside [2,29] was a zero pad row -> skip
    // (exact 0 contribution). Boundary yy iterations exec-mask a few lanes.
    if (tid < 240) {
        const int c    = tid / 15;
        const int rem  = tid % 15;
        const int pyg  = rem / 3;
        const int pxg  = rem % 3;
        const int row0 = pyg * 6;   // first padded h1 row needed
        const int col0 = pxg * 9;   // first padded h1 col needed
        const float bias = b2g[c];
        float acc[54];              // acc[t*9+u]: conv rows t=0..5, cols u=0..8
        #pragma unroll
        for (int i = 0; i < 54; ++i) acc[i] = bias;
        for (int ic = 0; ic < 8; ++ic) {
            float wreg[25];
            const float* wsrc = &w2g[(c*8+ic)*25];
            #pragma unroll
            for (int t = 0; t < 25; ++t) wreg[t] = wsrc[t];
            #pragma unroll
            for (int yy = 0; yy < 10; ++yy) {
                const int rr = row0 + yy;            // padded row id 0..33
                if ((unsigned)(rr - 2) > 27u) continue;  // pad row (zero) / oob
                const float* hp = &sb.h1p[(ic*28 + (rr-2))*H1W + col0];
                float rowv[13];
                #pragma unroll
                for (int j = 0; j < 13; ++j) rowv[j] = hp[j];
                #pragma unroll
                for (int t = 0; t < 6; ++t) {
                    const int ky = yy - t;
                    if (ky < 0 || ky > 4) continue;  // static after unroll
                    #pragma unroll
                    for (int kx = 0; kx < 5; ++kx) {
                        const float w = wreg[ky*5+kx];
                        #pragma unroll
                        for (int u = 0; u < 9; ++u)
                            acc[t*9+u] = fmaf(w, rowv[u+kx], acc[t*9+u]);
                    }
                }
            }
        }
        #pragma unroll
        for (int h = 0; h < 2; ++h) {
            const int py = pyg*2 + h;
            if (py < 9) {
                #pragma unroll
                for (int pxi = 0; pxi < 3; ++pxi) {
                    float m = acc[(h*3)*9 + pxi*3];
                    #pragma unroll
                    for (int dy = 0; dy < 3; ++dy)
                        #pragma unroll
                        for (int dx = 0; dx < 3; ++dx)
                            m = fmaxf(m, acc[(h*3+dy)*9 + pxi*3 + dx]);
                    sb.pbuf[c*81 + py*9 + pxg*3 + pxi] = fmaxf(m, 0.f);
                }
            }
        }
    }
    __syncthreads();
}

__device__ __forceinline__ void depthwise13(SharedBufs& sb, int tid)
{
    // out(y,x) = sum_{ky,kx} wker[ky*13+kx] * rp40[y+ky][x+kx]; 4 outputs/thread.
    if (tid < 196) {
        const int y  = tid / 7;
        const int x0 = (tid % 7) * 4;
        float a0=0.f, a1=0.f, a2=0.f, a3=0.f;
        #pragma unroll 1
        for (int ky = 0; ky < 13; ++ky) {
            const float4* rr = (const float4*)&sb.rp40[(y+ky)*RP40S + x0];
            float rv[16];
            #pragma unroll
            for (int q = 0; q < 4; ++q) {
                float4 t = rr[q];
                rv[q*4+0]=t.x; rv[q*4+1]=t.y; rv[q*4+2]=t.z; rv[q*4+3]=t.w;
            }
            const float* wr = &sb.wker[ky*13];
            #pragma unroll
            for (int kx = 0; kx < 13; ++kx) {
                const float w = wr[kx];
                a0 = fmaf(w, rv[kx+0], a0);
                a1 = fmaf(w, rv[kx+1], a1);
                a2 = fmaf(w, rv[kx+2], a2);
                a3 = fmaf(w, rv[kx+3], a3);
            }
        }
        float* dp = &sb.pbuf[y*28 + x0];
        dp[0]=a0; dp[1]=a1; dp[2]=a2; dp[3]=a3;
    }
}

__global__ __launch_bounds__(256) __attribute__((amdgpu_waves_per_eu(4)))
void modeld_fused(const float* __restrict__ x,
                  const float* __restrict__ n_w1, const float* __restrict__ n_b1,
                  const float* __restrict__ n_w2, const float* __restrict__ n_b2,
                  const float* __restrict__ n_wl, const float* __restrict__ n_bl,
                  const float* __restrict__ c_w1, const float* __restrict__ c_b1,
                  const float* __restrict__ c_w2, const float* __restrict__ c_b2,
                  const float* __restrict__ c_wl, const float* __restrict__ c_bl,
                  float* __restrict__ out,
                  int* __restrict__ counter, int B)
{
    __shared__ SharedBufs sb;
    const int tid = threadIdx.x;

    // one-time pad init: pads persist across samples (only interiors rewritten)
    for (int i = tid; i < 40*RP40S;   i += 256) sb.rp40[i] = -1.f;
    for (int i = tid; i < 8*28*H1W;   i += 256) sb.h1p[i]  = 0.f;

    while (true) {
        if (tid == 0) sb.next = atomicAdd(counter, 1);
        __syncthreads();                       // also orders pad init / prev sample
        const int b = sb.next;
        if (b >= B) break;                     // uniform exit

        // load x into the padded state buffer; keep own values in regs
        float cur[4] = {0.f, 0.f, 0.f, 0.f};
        #pragma unroll
        for (int q = 0; q < 4; ++q) {
            int i = tid + q*256;
            if (i < 784) {
                float v = x[b*784 + i];
                cur[q] = v;
                int yy = i / 28, xx = i % 28;
                sb.rp40[(yy+6)*RP40S + xx + 6] = v;
            }
        }
        __syncthreads();

        // ---- n-trunk -> num[0..9]
        trunk_pass(sb, tid, n_w1, n_b1, n_w2, n_b2);
        fc_tanh<10>(n_wl, n_bl, sb.pbuf, sb.num_s, tid);
        __syncthreads();

        float o[4];
        {
            const float n0 = sb.num_s[0];
            #pragma unroll
            for (int q = 0; q < 4; ++q) o[q] = n0 * cur[q];
        }

        // ---- 9 iterations
        for (int k = 1; k <= 9; ++k) {
            trunk_pass(sb, tid, c_w1, c_b1, c_w2, c_b2);       // rp40 -> pbuf[1296]
            fc_tanh<169>(c_wl, c_bl, sb.pbuf, sb.wker, tid);   // pbuf -> wker
            __syncthreads();
            depthwise13(sb, tid);                              // rp40,wker -> pbuf[0..783]
            __syncthreads();
            const float nk = sb.num_s[k];
            #pragma unroll
            for (int q = 0; q < 4; ++q) {
                int i = tid + q*256;
                if (i < 784) {
                    float v = sb.pbuf[i];
                    o[q] = fmaf(nk, v, o[q]);
                    int yy = i / 28, xx = i % 28;
                    sb.rp40[(yy+6)*RP40S + xx + 6] = v;
                }
            }
            __syncthreads();
        }

        #pragma unroll
        for (int q = 0; q < 4; ++q) {
            int i = tid + q*256;
            if (i < 784) out[b*784 + i] = o[q];
        }
        // no barrier needed here: next iteration's grab+sync orders sb.next,
        // and all LDS writes for the next sample happen after that sync.
    }
}

extern "C" void kernel_launch(void* const* d_in, const int* in_sizes, int n_in,
                              void* d_out, int out_size, void* d_ws, size_t ws_size,
                              hipStream_t stream)
{
    const float* x    = (const float*)d_in[0];
    const float* n_w1 = (const float*)d_in[1];
    const float* n_b1 = (const float*)d_in[2];
    const float* n_w2 = (const float*)d_in[3];
    const float* n_b2 = (const float*)d_in[4];
    const float* n_wl = (const float*)d_in[5];
    const float* n_bl = (const float*)d_in[6];
    const float* c_w1 = (const float*)d_in[7];
    const float* c_b1 = (const float*)d_in[8];
    const float* c_w2 = (const float*)d_in[9];
    const float* c_b2 = (const float*)d_in[10];
    const float* c_wl = (const float*)d_in[11];
    const float* c_bl = (const float*)d_in[12];
    float* out = (float*)d_out;

    const int B = in_sizes[0] / 784;
    hipMemsetAsync(d_ws, 0, sizeof(int), stream);   // work-stealing counter reset
    const int grid = B < 1024 ? B : 1024;           // 4 blocks/CU x 256 CUs
    hipLaunchKernelGGL(modeld_fused, dim3(grid), dim3(256), 0, stream,
                       x, n_w1, n_b1, n_w2, n_b2, n_wl, n_bl,
                       c_w1, c_b1, c_w2, c_b2, c_wl, c_bl, out,
                       (int*)d_ws, B);
}

// Round 6
// 1388.508 us; speedup vs baseline: 6.3201x; 6.3201x over previous
//
#include <hip/hip_runtime.h>
#include <math.h>

// Per-sample fully-fused iterated CNN. Persistent blocks, 256 threads, atomic
// work-stealing. 4 blocks/CU at FULL fp32 (rounds 3/4: any mantissa
// compression is chaotically amplified by the ~10x/iter state growth).
// LDS = 40720 B (validated round 5): rp32 removed via exact algebraic pad
// correction; h1p has no row pads; w1/b1/w2/b2 read from global (L1).
// VGPR: wave-based occupancy hints are BROKEN on this toolchain -- both
// __launch_bounds__(256,3) (->84) and amdgpu_waves_per_eu(4) (->64) delivered
// 2x the requested waves and catastrophic spills. Instead: (a) conv2
// restructured so each thread computes ONE pooled row at a time (acc[27], two
// sequential halves; same FMA count, +40% cheap LDS row reads), live set
// ~90 regs; (b) raw-count pin amdgpu_num_vgpr(128) -> 4 waves/SIMD.
#define RP40S 44   // (-1)-padded 40x44 state (16B-aligned rows)
#define H1W   31   // h1 col stride: 2 left pads + 28 + 1 right pad (zeros);
                   // 31 = -1 mod 32 -> worst 2-way bank alias (free on CDNA4)

struct SharedBufs {
    float rp40[40*RP40S];   //  7040 B  (state, -1 pads, persists)
    float h1p[8*28*H1W];    // 27776 B  (conv1 activations, fp32, zero col-pads)
    float pbuf[1296];       //  5184 B  (pooled feats; reused as new-r tmp[784])
    float wker[169];        //   676 B
    float num_s[10];        //    40 B
    int   next;             //     4 B  (work-stealing broadcast slot)
};                          // 40720 B -> 40960 block = exactly 160KB/4

template<int OUT>
__device__ __forceinline__ void fc_tanh(const float* __restrict__ Wg,
                                        const float* __restrict__ bg,
                                        const float* __restrict__ p,
                                        float* __restrict__ dst, int tid)
{
    if (tid < OUT) {
        float a[8];
        #pragma unroll
        for (int u = 0; u < 8; ++u) a[u] = 0.f;
        #pragma unroll 2
        for (int i0 = 0; i0 < 1296; i0 += 8) {
            #pragma unroll
            for (int u = 0; u < 8; ++u)
                a[u] = fmaf(p[i0+u], Wg[(i0+u)*OUT + tid], a[u]);
        }
        float s = ((a[0]+a[1])+(a[2]+a[3])) + ((a[4]+a[5])+(a[6]+a[7])) + bg[tid];
        dst[tid] = tanhf(s);
    }
}

__device__ __forceinline__ void trunk_pass(SharedBufs& sb, int tid,
                                           const float* __restrict__ w1g,
                                           const float* __restrict__ b1g,
                                           const float* __restrict__ w2g,
                                           const float* __restrict__ b2g)
{
    // ---- conv1 5x5 pad2 + relu -> h1p. thread = (y, c): c=tid&7 so a y-group
    // of 8 lanes broadcasts the same rp40 row. Reads the -1-padded rp40 (pad
    // depth <=2 used); exact correction: true = computed + sum_oob(w), with
    // sum_oob decomposed into row-restricted column sums csR[kx] folded into
    // the acc init (validated round 5).
    if (tid < 224) {
        const int c = tid & 7;
        const int y = tid >> 3;
        float wreg[25];
        #pragma unroll
        for (int t = 0; t < 25; ++t) wreg[t] = w1g[c*25 + t];
        float csR[5];
        float S_all = 0.f, SR = 0.f;
        #pragma unroll
        for (int kx = 0; kx < 5; ++kx) {
            float a = wreg[kx] + wreg[5+kx] + wreg[10+kx] + wreg[15+kx] + wreg[20+kx];
            float ex = 0.f;
            if (y == 0)       ex = wreg[kx] + wreg[5+kx];   // rows ky=0,1 oob
            else if (y == 1)  ex = wreg[kx];                // row ky=0 oob
            if (y == 26)      ex += wreg[20+kx];            // row ky=4 oob
            else if (y == 27) ex += wreg[15+kx] + wreg[20+kx];
            csR[kx] = a - ex;
            S_all += a; SR += csR[kx];
        }
        const float corrI = S_all - SR;       // rows-oob, all kx (0 for inner y)
        const float bias  = b1g[c];
        float acc[28];
        #pragma unroll
        for (int x = 0; x < 28; ++x) acc[x] = bias + corrI;
        acc[0]  += csR[0] + csR[1];           // cols kx=0,1 oob at x=0
        acc[1]  += csR[0];
        acc[26] += csR[4];
        acc[27] += csR[3] + csR[4];
        #pragma unroll
        for (int ky = 0; ky < 5; ++ky) {
            // rp40 rows y+4..y+8, cols 4..35 (state cols -2..29), 16B-aligned
            const float4* rr = (const float4*)&sb.rp40[(y+4+ky)*RP40S + 4];
            float rv[32];
            #pragma unroll
            for (int q = 0; q < 8; ++q) {
                float4 t = rr[q];
                rv[q*4+0]=t.x; rv[q*4+1]=t.y; rv[q*4+2]=t.z; rv[q*4+3]=t.w;
            }
            #pragma unroll
            for (int kx = 0; kx < 5; ++kx) {
                const float w = wreg[ky*5+kx];
                #pragma unroll
                for (int x = 0; x < 28; ++x) acc[x] = fmaf(w, rv[x+kx], acc[x]);
            }
        }
        float* hp = &sb.h1p[(c*28 + y)*H1W + 2];
        #pragma unroll
        for (int x = 0; x < 28; ++x) hp[x] = fmaxf(acc[x], 0.f);
    }
    __syncthreads();

    // ---- conv2 5x5 pad2 + relu + maxpool3 -> pbuf[1296].
    // 240 threads cover 16c x 5pyg x 3pxg; each thread does its 2 pooled rows
    // SEQUENTIALLY (h=0,1): acc[27] (3 conv rows x 9 cols) instead of acc[54]
    // -- halves the live set (~90 regs) so VGPR<=128 holds without spill.
    // Same FMA count; +4 h1 row reads/ic (LDS, cheap); wreg reloaded per half
    // (L1-resident broadcast). pyg==4,h==1 breaks early (py 9 doesn't exist).
    if (tid < 240) {
        const int c    = tid / 15;
        const int rem  = tid % 15;
        const int pyg  = rem / 3;
        const int pxg  = rem % 3;
        const int col0 = pxg * 9;   // first padded h1 col needed
        const float bias = b2g[c];
        #pragma unroll 1
        for (int h = 0; h < 2; ++h) {
            const int py = pyg*2 + h;
            if (py >= 9) break;            // only pyg==4,h==1
            const int crow0 = py * 3;      // first conv row (=first padded h1 row)
            float acc[27];                 // acc[t*9+u]: conv rows t=0..2, cols u=0..8
            #pragma unroll
            for (int i = 0; i < 27; ++i) acc[i] = bias;
            for (int ic = 0; ic < 8; ++ic) {
                float wreg[25];
                const float* wsrc = &w2g[(c*8+ic)*25];
                #pragma unroll
                for (int t = 0; t < 25; ++t) wreg[t] = wsrc[t];
                #pragma unroll
                for (int yy = 0; yy < 7; ++yy) {
                    const int rr = crow0 + yy;               // padded row id 0..32
                    if ((unsigned)(rr - 2) > 27u) continue;  // pad row (zero) / oob
                    const float* hp = &sb.h1p[(ic*28 + (rr-2))*H1W + col0];
                    float rowv[13];
                    #pragma unroll
                    for (int j = 0; j < 13; ++j) rowv[j] = hp[j];
                    #pragma unroll
                    for (int t = 0; t < 3; ++t) {
                        const int ky = yy - t;
                        if (ky < 0 || ky > 4) continue;      // static after unroll
                        #pragma unroll
                        for (int kx = 0; kx < 5; ++kx) {
                            const float w = wreg[ky*5+kx];
                            #pragma unroll
                            for (int u = 0; u < 9; ++u)
                                acc[t*9+u] = fmaf(w, rowv[u+kx], acc[t*9+u]);
                        }
                    }
                }
            }
            #pragma unroll
            for (int pxi = 0; pxi < 3; ++pxi) {
                float m = acc[pxi*3];
                #pragma unroll
                for (int dy = 0; dy < 3; ++dy)
                    #pragma unroll
                    for (int dx = 0; dx < 3; ++dx)
                        m = fmaxf(m, acc[dy*9 + pxi*3 + dx]);
                sb.pbuf[c*81 + py*9 + pxg*3 + pxi] = fmaxf(m, 0.f);
            }
        }
    }
    __syncthreads();
}

__device__ __forceinline__ void depthwise13(SharedBufs& sb, int tid)
{
    // out(y,x) = sum_{ky,kx} wker[ky*13+kx] * rp40[y+ky][x+kx]; 4 outputs/thread.
    if (tid < 196) {
        const int y  = tid / 7;
        const int x0 = (tid % 7) * 4;
        float a0=0.f, a1=0.f, a2=0.f, a3=0.f;
        #pragma unroll 1
        for (int ky = 0; ky < 13; ++ky) {
            const float4* rr = (const float4*)&sb.rp40[(y+ky)*RP40S + x0];
            float rv[16];
            #pragma unroll
            for (int q = 0; q < 4; ++q) {
                float4 t = rr[q];
                rv[q*4+0]=t.x; rv[q*4+1]=t.y; rv[q*4+2]=t.z; rv[q*4+3]=t.w;
            }
            const float* wr = &sb.wker[ky*13];
            #pragma unroll
            for (int kx = 0; kx < 13; ++kx) {
                const float w = wr[kx];
                a0 = fmaf(w, rv[kx+0], a0);
                a1 = fmaf(w, rv[kx+1], a1);
                a2 = fmaf(w, rv[kx+2], a2);
                a3 = fmaf(w, rv[kx+3], a3);
            }
        }
        float* dp = &sb.pbuf[y*28 + x0];
        dp[0]=a0; dp[1]=a1; dp[2]=a2; dp[3]=a3;
    }
}

__global__ __launch_bounds__(256) __attribute__((amdgpu_num_vgpr(128)))
void modeld_fused(const float* __restrict__ x,
                  const float* __restrict__ n_w1, const float* __restrict__ n_b1,
                  const float* __restrict__ n_w2, const float* __restrict__ n_b2,
                  const float* __restrict__ n_wl, const float* __restrict__ n_bl,
                  const float* __restrict__ c_w1, const float* __restrict__ c_b1,
                  const float* __restrict__ c_w2, const float* __restrict__ c_b2,
                  const float* __restrict__ c_wl, const float* __restrict__ c_bl,
                  float* __restrict__ out,
                  int* __restrict__ counter, int B)
{
    __shared__ SharedBufs sb;
    const int tid = threadIdx.x;

    // one-time pad init: pads persist across samples (only interiors rewritten)
    for (int i = tid; i < 40*RP40S;   i += 256) sb.rp40[i] = -1.f;
    for (int i = tid; i < 8*28*H1W;   i += 256) sb.h1p[i]  = 0.f;

    while (true) {
        if (tid == 0) sb.next = atomicAdd(counter, 1);
        __syncthreads();                       // also orders pad init / prev sample
        const int b = sb.next;
        if (b >= B) break;                     // uniform exit

        // load x into the padded state buffer; keep own values in regs
        float cur[4] = {0.f, 0.f, 0.f, 0.f};
        #pragma unroll
        for (int q = 0; q < 4; ++q) {
            int i = tid + q*256;
            if (i < 784) {
                float v = x[b*784 + i];
                cur[q] = v;
                int yy = i / 28, xx = i % 28;
                sb.rp40[(yy+6)*RP40S + xx + 6] = v;
            }
        }
        __syncthreads();

        // ---- n-trunk -> num[0..9]
        trunk_pass(sb, tid, n_w1, n_b1, n_w2, n_b2);
        fc_tanh<10>(n_wl, n_bl, sb.pbuf, sb.num_s, tid);
        __syncthreads();

        float o[4];
        {
            const float n0 = sb.num_s[0];
            #pragma unroll
            for (int q = 0; q < 4; ++q) o[q] = n0 * cur[q];
        }

        // ---- 9 iterations
        for (int k = 1; k <= 9; ++k) {
            trunk_pass(sb, tid, c_w1, c_b1, c_w2, c_b2);       // rp40 -> pbuf[1296]
            fc_tanh<169>(c_wl, c_bl, sb.pbuf, sb.wker, tid);   // pbuf -> wker
            __syncthreads();
            depthwise13(sb, tid);                              // rp40,wker -> pbuf[0..783]
            __syncthreads();
            const float nk = sb.num_s[k];
            #pragma unroll
            for (int q = 0; q < 4; ++q) {
                int i = tid + q*256;
                if (i < 784) {
                    float v = sb.pbuf[i];
                    o[q] = fmaf(nk, v, o[q]);
                    int yy = i / 28, xx = i % 28;
                    sb.rp40[(yy+6)*RP40S + xx + 6] = v;
                }
            }
            __syncthreads();
        }

        #pragma unroll
        for (int q = 0; q < 4; ++q) {
            int i = tid + q*256;
            if (i < 784) out[b*784 + i] = o[q];
        }
        // no barrier needed here: next iteration's grab+sync orders sb.next,
        // and all LDS writes for the next sample happen after that sync.
    }
}

extern "C" void kernel_launch(void* const* d_in, const int* in_sizes, int n_in,
                              void* d_out, int out_size, void* d_ws, size_t ws_size,
                              hipStream_t stream)
{
    const float* x    = (const float*)d_in[0];
    const float* n_w1 = (const float*)d_in[1];
    const float* n_b1 = (const float*)d_in[2];
    const float* n_w2 = (const float*)d_in[3];
    const float* n_b2 = (const float*)d_in[4];
    const float* n_wl = (const float*)d_in[5];
    const float* n_bl = (const float*)d_in[6];
    const float* c_w1 = (const float*)d_in[7];
    const float* c_b1 = (const float*)d_in[8];
    const float* c_w2 = (const float*)d_in[9];
    const float* c_b2 = (const float*)d_in[10];
    const float* c_wl = (const float*)d_in[11];
    const float* c_bl = (const float*)d_in[12];
    float* out = (float*)d_out;

    const int B = in_sizes[0] / 784;
    hipMemsetAsync(d_ws, 0, sizeof(int), stream);   // work-stealing counter reset
    const int grid = B < 1024 ? B : 1024;           // 4 blocks/CU x 256 CUs
    hipLaunchKernelGGL(modeld_fused, dim3(grid), dim3(256), 0, stream,
                       x, n_w1, n_b1, n_w2, n_b2, n_wl, n_bl,
                       c_w1, c_b1, c_w2, c_b2, c_wl, c_bl, out,
                       (int*)d_ws, B);
}

// Round 7
// 1342.260 us; speedup vs baseline: 6.5379x; 1.0345x over previous
//
#include <hip/hip_runtime.h>
#include <math.h>

// Per-sample fully-fused iterated CNN. Persistent blocks, 256 threads, atomic
// work-stealing, 4 blocks/CU (LDS 40752B, VGPR<=128 via amdgpu_num_vgpr --
// wave-based hints are broken: launch_bounds(256,3)->84, waves_per_eu(4)->64,
// both spilled catastrophically). FULL fp32 (rounds 3/4: fp16/bf16 h1 storage
// is chaotically amplified by the ~10x/iter state growth -> 11x over thresh).
// Round-6 lesson: occupancy 3->4 blocks was NET-ZERO -> no longer wave-
// starved; this round attacks in-wave latency: conv2 ping-pong row prefetch,
// fc unroll 4 (32 outstanding L2 loads), dw register epilogue (pbuf state
// round-trip eliminated, float4 x-load/out-store under the dw mapping).
// NOTE: SQ_LDS_BANK_CONFLICT ~1.6-2e8 is ~1.5-2/LDS-inst across ALL variants
// = benign wave64 2-way aliasing (free on CDNA4). Phantom metric here.
#define RP40S 44   // (-1)-padded 40x44 state (16B-aligned rows)
#define H1W   31   // h1 col stride: 2 left pads + 28 + 1 right pad (zeros)

struct SharedBufs {
    float rp40[40*RP40S];   //  7040 B  (state, -1 pads, persists)
    float h1p[8*28*H1W];    // 27776 B  (conv1 activations, fp32, zero col-pads)
    float pbuf[1296];       //  5184 B  (pooled feats -> fc input)
    float wker[169];        //   676 B
    float num_s[10];        //    40 B
    int   next;             //     4 B  (work-stealing broadcast slot)
};                          // 40752 B -> 40960 block = exactly 160KB/4

template<int OUT>
__device__ __forceinline__ void fc_tanh(const float* __restrict__ Wg,
                                        const float* __restrict__ bg,
                                        const float* __restrict__ p,
                                        float* __restrict__ dst, int tid)
{
    if (tid < OUT) {
        float a[8];
        #pragma unroll
        for (int u = 0; u < 8; ++u) a[u] = 0.f;
        #pragma unroll 4
        for (int i0 = 0; i0 < 1296; i0 += 8) {
            #pragma unroll
            for (int u = 0; u < 8; ++u)
                a[u] = fmaf(p[i0+u], Wg[(i0+u)*OUT + tid], a[u]);
        }
        float s = ((a[0]+a[1])+(a[2]+a[3])) + ((a[4]+a[5])+(a[6]+a[7])) + bg[tid];
        dst[tid] = tanhf(s);
    }
}

// conv2 helpers: static-indexed row load (clamped, always safe) and FMA block.
#define C2_LOADROW(dst, YY) {                                                  \
    int rr_ = crow0 + (YY); rr_ = rr_ < 2 ? 2 : (rr_ > 29 ? 29 : rr_);         \
    const float* hp_ = plane + (rr_ - 2)*H1W;                                  \
    _Pragma("unroll") for (int j = 0; j < 13; ++j) dst[j] = hp_[j]; }

#define C2_FMAROW(src, YY)                                                     \
    if ((unsigned)(crow0 + (YY) - 2) <= 27u) {                                 \
      _Pragma("unroll") for (int t = 0; t < 3; ++t) {                          \
        const int ky_ = (YY) - t;                                              \
        if (ky_ >= 0 && ky_ <= 4) {                                            \
          _Pragma("unroll") for (int kx = 0; kx < 5; ++kx) {                   \
            const float w_ = wreg[ky_*5+kx];                                   \
            _Pragma("unroll") for (int u = 0; u < 9; ++u)                      \
              acc[t*9+u] = fmaf(w_, src[u+kx], acc[t*9+u]); } } } }

__device__ __forceinline__ void trunk_pass(SharedBufs& sb, int tid,
                                           const float* __restrict__ w1g,
                                           const float* __restrict__ b1g,
                                           const float* __restrict__ w2g,
                                           const float* __restrict__ b2g)
{
    // ---- conv1 5x5 pad2 + relu -> h1p. thread = (y, c): c=tid&7 so a y-group
    // of 8 lanes broadcasts the same rp40 row. Reads the -1-padded rp40 with
    // exact algebraic pad correction folded into acc init (validated r5/r6).
    if (tid < 224) {
        const int c = tid & 7;
        const int y = tid >> 3;
        float wreg[25];
        #pragma unroll
        for (int t = 0; t < 25; ++t) wreg[t] = w1g[c*25 + t];
        float csR[5];
        float S_all = 0.f, SR = 0.f;
        #pragma unroll
        for (int kx = 0; kx < 5; ++kx) {
            float a = wreg[kx] + wreg[5+kx] + wreg[10+kx] + wreg[15+kx] + wreg[20+kx];
            float ex = 0.f;
            if (y == 0)       ex = wreg[kx] + wreg[5+kx];   // rows ky=0,1 oob
            else if (y == 1)  ex = wreg[kx];                // row ky=0 oob
            if (y == 26)      ex += wreg[20+kx];            // row ky=4 oob
            else if (y == 27) ex += wreg[15+kx] + wreg[20+kx];
            csR[kx] = a - ex;
            S_all += a; SR += csR[kx];
        }
        const float corrI = S_all - SR;       // rows-oob, all kx (0 for inner y)
        const float bias  = b1g[c];
        float acc[28];
        #pragma unroll
        for (int x = 0; x < 28; ++x) acc[x] = bias + corrI;
        acc[0]  += csR[0] + csR[1];           // cols kx=0,1 oob at x=0
        acc[1]  += csR[0];
        acc[26] += csR[4];
        acc[27] += csR[3] + csR[4];
        #pragma unroll
        for (int ky = 0; ky < 5; ++ky) {
            // rp40 rows y+4..y+8, cols 4..35 (state cols -2..29), 16B-aligned
            const float4* rr = (const float4*)&sb.rp40[(y+4+ky)*RP40S + 4];
            float rv[32];
            #pragma unroll
            for (int q = 0; q < 8; ++q) {
                float4 t = rr[q];
                rv[q*4+0]=t.x; rv[q*4+1]=t.y; rv[q*4+2]=t.z; rv[q*4+3]=t.w;
            }
            #pragma unroll
            for (int kx = 0; kx < 5; ++kx) {
                const float w = wreg[ky*5+kx];
                #pragma unroll
                for (int x = 0; x < 28; ++x) acc[x] = fmaf(w, rv[x+kx], acc[x]);
            }
        }
        float* hp = &sb.h1p[(c*28 + y)*H1W + 2];
        #pragma unroll
        for (int x = 0; x < 28; ++x) hp[x] = fmaxf(acc[x], 0.f);
    }
    __syncthreads();

    // ---- conv2 5x5 pad2 + relu + maxpool3 -> pbuf[1296].
    // 240 threads cover 16c x 5pyg x 3pxg; 2 pooled rows sequentially
    // (acc[27], live set ~90+13 regs, fits 128). Rows double-buffered ra/rb:
    // row yy+1 loads issue while row yy's 135 FMAs run -> LDS latency hidden.
    // w2/b2 from global (12.8 KB, L1-resident broadcast; 15 lanes share c).
    if (tid < 240) {
        const int c    = tid / 15;
        const int rem  = tid % 15;
        const int pyg  = rem / 3;
        const int pxg  = rem % 3;
        const int col0 = pxg * 9;   // first padded h1 col needed
        const float bias = b2g[c];
        #pragma unroll 1
        for (int h = 0; h < 2; ++h) {
            const int py = pyg*2 + h;
            if (py >= 9) break;            // only pyg==4,h==1
            const int crow0 = py * 3;      // first conv row (=first padded h1 row)
            float acc[27];                 // acc[t*9+u]: conv rows t=0..2, cols u=0..8
            #pragma unroll
            for (int i = 0; i < 27; ++i) acc[i] = bias;
            for (int ic = 0; ic < 8; ++ic) {
                float wreg[25];
                const float* wsrc = &w2g[(c*8+ic)*25];
                #pragma unroll
                for (int t = 0; t < 25; ++t) wreg[t] = wsrc[t];
                const float* plane = &sb.h1p[ic*28*H1W + col0];
                float ra[13], rb[13];
                C2_LOADROW(ra, 0)
                C2_LOADROW(rb, 1)  C2_FMAROW(ra, 0)
                C2_LOADROW(ra, 2)  C2_FMAROW(rb, 1)
                C2_LOADROW(rb, 3)  C2_FMAROW(ra, 2)
                C2_LOADROW(ra, 4)  C2_FMAROW(rb, 3)
                C2_LOADROW(rb, 5)  C2_FMAROW(ra, 4)
                C2_LOADROW(ra, 6)  C2_FMAROW(rb, 5)
                                   C2_FMAROW(ra, 6)
            }
            #pragma unroll
            for (int pxi = 0; pxi < 3; ++pxi) {
                float m = acc[pxi*3];
                #pragma unroll
                for (int dy = 0; dy < 3; ++dy)
                    #pragma unroll
                    for (int dx = 0; dx < 3; ++dx)
                        m = fmaxf(m, acc[dy*9 + pxi*3 + dx]);
                sb.pbuf[c*81 + py*9 + pxg*3 + pxi] = fmaxf(m, 0.f);
            }
        }
    }
    __syncthreads();
}

__device__ __forceinline__ void depthwise13_regs(SharedBufs& sb, int y, int x0,
                                                 float& a0, float& a1,
                                                 float& a2, float& a3)
{
    // out(y,x) = sum_{ky,kx} wker[ky*13+kx] * rp40[y+ky][x+kx]; results stay
    // in registers -- caller barriers, then writes rp40/o directly (no pbuf).
    a0=0.f; a1=0.f; a2=0.f; a3=0.f;
    #pragma unroll 1
    for (int ky = 0; ky < 13; ++ky) {
        const float4* rr = (const float4*)&sb.rp40[(y+ky)*RP40S + x0];
        float rv[16];
        #pragma unroll
        for (int q = 0; q < 4; ++q) {
            float4 t = rr[q];
            rv[q*4+0]=t.x; rv[q*4+1]=t.y; rv[q*4+2]=t.z; rv[q*4+3]=t.w;
        }
        const float* wr = &sb.wker[ky*13];
        #pragma unroll
        for (int kx = 0; kx < 13; ++kx) {
            const float w = wr[kx];
            a0 = fmaf(w, rv[kx+0], a0);
            a1 = fmaf(w, rv[kx+1], a1);
            a2 = fmaf(w, rv[kx+2], a2);
            a3 = fmaf(w, rv[kx+3], a3);
        }
    }
}

__global__ __launch_bounds__(256) __attribute__((amdgpu_num_vgpr(128)))
void modeld_fused(const float* __restrict__ x,
                  const float* __restrict__ n_w1, const float* __restrict__ n_b1,
                  const float* __restrict__ n_w2, const float* __restrict__ n_b2,
                  const float* __restrict__ n_wl, const float* __restrict__ n_bl,
                  const float* __restrict__ c_w1, const float* __restrict__ c_b1,
                  const float* __restrict__ c_w2, const float* __restrict__ c_b2,
                  const float* __restrict__ c_wl, const float* __restrict__ c_bl,
                  float* __restrict__ out,
                  int* __restrict__ counter, int B)
{
    __shared__ SharedBufs sb;
    const int tid = threadIdx.x;
    const int dy  = tid / 7;          // dw/state mapping: thread<196 owns
    const int dx0 = (tid % 7) * 4;    // outputs (dy, dx0..dx0+3)

    // one-time pad init: pads persist across samples (only interiors rewritten)
    for (int i = tid; i < 40*RP40S;   i += 256) sb.rp40[i] = -1.f;
    for (int i = tid; i < 8*28*H1W;   i += 256) sb.h1p[i]  = 0.f;

    while (true) {
        if (tid == 0) sb.next = atomicAdd(counter, 1);
        __syncthreads();                       // also orders pad init / prev sample
        const int b = sb.next;
        if (b >= B) break;                     // uniform exit

        // load x (float4 per dw mapping) into rp40 interior; keep in regs
        float cur[4] = {0.f, 0.f, 0.f, 0.f};
        if (tid < 196) {
            const float4 t = *(const float4*)&x[b*784 + dy*28 + dx0];
            cur[0]=t.x; cur[1]=t.y; cur[2]=t.z; cur[3]=t.w;
            float* rp = &sb.rp40[(dy+6)*RP40S + dx0 + 6];
            rp[0]=t.x; rp[1]=t.y; rp[2]=t.z; rp[3]=t.w;
        }
        __syncthreads();

        // ---- n-trunk -> num[0..9]
        trunk_pass(sb, tid, n_w1, n_b1, n_w2, n_b2);
        fc_tanh<10>(n_wl, n_bl, sb.pbuf, sb.num_s, tid);
        __syncthreads();

        float o[4];
        {
            const float n0 = sb.num_s[0];
            #pragma unroll
            for (int q = 0; q < 4; ++q) o[q] = n0 * cur[q];
        }

        // ---- 9 iterations
        for (int k = 1; k <= 9; ++k) {
            trunk_pass(sb, tid, c_w1, c_b1, c_w2, c_b2);       // rp40 -> pbuf[1296]
            fc_tanh<169>(c_wl, c_bl, sb.pbuf, sb.wker, tid);   // pbuf -> wker
            __syncthreads();
            float a0, a1, a2, a3;
            if (tid < 196) depthwise13_regs(sb, dy, dx0, a0, a1, a2, a3);
            __syncthreads();                   // all rp40 reads done before writes
            if (tid < 196) {
                const float nk = sb.num_s[k];
                o[0] = fmaf(nk, a0, o[0]);
                o[1] = fmaf(nk, a1, o[1]);
                o[2] = fmaf(nk, a2, o[2]);
                o[3] = fmaf(nk, a3, o[3]);
                float* rp = &sb.rp40[(dy+6)*RP40S + dx0 + 6];
                rp[0]=a0; rp[1]=a1; rp[2]=a2; rp[3]=a3;
            }
            __syncthreads();                   // new state visible to next conv1
        }

        if (tid < 196)
            *(float4*)&out[b*784 + dy*28 + dx0] = make_float4(o[0], o[1], o[2], o[3]);
        // no barrier needed: next iteration's grab+sync orders everything
    }
}

extern "C" void kernel_launch(void* const* d_in, const int* in_sizes, int n_in,
                              void* d_out, int out_size, void* d_ws, size_t ws_size,
                              hipStream_t stream)
{
    const float* x    = (const float*)d_in[0];
    const float* n_w1 = (const float*)d_in[1];
    const float* n_b1 = (const float*)d_in[2];
    const float* n_w2 = (const float*)d_in[3];
    const float* n_b2 = (const float*)d_in[4];
    const float* n_wl = (const float*)d_in[5];
    const float* n_bl = (const float*)d_in[6];
    const float* c_w1 = (const float*)d_in[7];
    const float* c_b1 = (const float*)d_in[8];
    const float* c_w2 = (const float*)d_in[9];
    const float* c_b2 = (const float*)d_in[10];
    const float* c_wl = (const float*)d_in[11];
    const float* c_bl = (const float*)d_in[12];
    float* out = (float*)d_out;

    const int B = in_sizes[0] / 784;
    hipMemsetAsync(d_ws, 0, sizeof(int), stream);   // work-stealing counter reset
    const int grid = B < 1024 ? B : 1024;           // 4 blocks/CU x 256 CUs
    hipLaunchKernelGGL(modeld_fused, dim3(grid), dim3(256), 0, stream,
                       x, n_w1, n_b1, n_w2, n_b2, n_wl, n_bl,
                       c_w1, c_b1, c_w2, c_b2, c_wl, c_bl, out,
                       (int*)d_ws, B);
}